// Round 10
// baseline (1332.461 us; speedup 1.0000x reference)
//
#include <hip/hip_runtime.h>
#include <hip/hip_bf16.h>
#include <math.h>

// Problem constants (fixed by the reference)
#define GN 100000   // nodes
#define GE 1200000  // edges
#define GB 128      // graphs
#define GF 92       // raw features
#define GD 64       // hidden dim
#define GL 3        // CGConv layers
#define GZ 129      // 2*D+1

// round-to-nearest-even fp32 -> bf16 (returned in low 16 bits)
__device__ __forceinline__ unsigned int f2bf_rne(float x)
{
    unsigned int u = __float_as_uint(x);
    u += 0x7fffu + ((u >> 16) & 1u);
    return u >> 16;
}

// ---------------------------------------------------------------------------
// Fused pre-MLP (3 layers) + P0, lane = node. Layers chain through per-lane
// registers (h[64] lives in VGPRs) -- no global round-trip, no broadcast.
// Weight addresses are lane-invariant -> scalar s_load streams shared by the
// wave's 64 nodes (the R9 pattern that fixed the dense layers).
// ---------------------------------------------------------------------------
__global__ __launch_bounds__(256) void premlp_kernel(
    const float* __restrict__ X,
    const float* __restrict__ W0, const float* __restrict__ b0,
    const float* __restrict__ W1, const float* __restrict__ b1,
    const float* __restrict__ W2, const float* __restrict__ b2,
    const float* __restrict__ WfN, const float* __restrict__ WsN,
    float* __restrict__ hout, unsigned int* __restrict__ Pout, int N)
{
    int n = blockIdx.x * 256 + threadIdx.x;   // lane = node
    if (n >= N) return;

    float h[64], h2[64];

    // layer 0: K=92, X row per-lane (L1-resident across j-tiles)
    const float4* __restrict__ row4 = (const float4*)(X + (size_t)n * GF);
#pragma unroll
    for (int jt = 0; jt < 8; ++jt) {
        float acc[8];
#pragma unroll
        for (int j = 0; j < 8; ++j) acc[j] = b0[jt * 8 + j];
        for (int c = 0; c < 23; ++c) {
            float4 v = row4[c];
            const float* __restrict__ w = W0 + (c * 4) * 64 + jt * 8;  // uniform
#pragma unroll
            for (int j = 0; j < 8; ++j) {
                acc[j] = fmaf(v.x, w[j], acc[j]);
                acc[j] = fmaf(v.y, w[64 + j], acc[j]);
                acc[j] = fmaf(v.z, w[128 + j], acc[j]);
                acc[j] = fmaf(v.w, w[192 + j], acc[j]);
            }
        }
#pragma unroll
        for (int j = 0; j < 8; ++j) h[jt * 8 + j] = fmaxf(acc[j], 0.f);
    }

    // layer 1: input = h registers
#pragma unroll
    for (int jt = 0; jt < 8; ++jt) {
        float acc[8];
#pragma unroll
        for (int j = 0; j < 8; ++j) acc[j] = b1[jt * 8 + j];
#pragma unroll
        for (int k = 0; k < 64; ++k) {
            const float* __restrict__ w = W1 + k * 64 + jt * 8;
#pragma unroll
            for (int j = 0; j < 8; ++j) acc[j] = fmaf(h[k], w[j], acc[j]);
        }
#pragma unroll
        for (int j = 0; j < 8; ++j) h2[jt * 8 + j] = fmaxf(acc[j], 0.f);
    }

    // layer 2: h2 -> h
#pragma unroll
    for (int jt = 0; jt < 8; ++jt) {
        float acc[8];
#pragma unroll
        for (int j = 0; j < 8; ++j) acc[j] = b2[jt * 8 + j];
#pragma unroll
        for (int k = 0; k < 64; ++k) {
            const float* __restrict__ w = W2 + k * 64 + jt * 8;
#pragma unroll
            for (int j = 0; j < 8; ++j) acc[j] = fmaf(h2[k], w[j], acc[j]);
        }
#pragma unroll
        for (int j = 0; j < 8; ++j) h[jt * 8 + j] = fmaxf(acc[j], 0.f);
    }

    // store h
    float4* __restrict__ op = (float4*)(hout + (size_t)n * 64);
#pragma unroll
    for (int c = 0; c < 16; ++c)
        op[c] = make_float4(h[c * 4], h[c * 4 + 1], h[c * 4 + 2], h[c * 4 + 3]);

    // P0 projection (src half of both layer-0 gates), packed bf16
#pragma unroll
    for (int jt = 0; jt < 8; ++jt) {
        float aF[8], aS[8];
#pragma unroll
        for (int j = 0; j < 8; ++j) { aF[j] = 0.f; aS[j] = 0.f; }
#pragma unroll
        for (int k = 0; k < 64; ++k) {
            const float* __restrict__ wf = WfN + k * 64 + jt * 8;
            const float* __restrict__ ws = WsN + k * 64 + jt * 8;
#pragma unroll
            for (int j = 0; j < 8; ++j) {
                aF[j] = fmaf(h[k], wf[j], aF[j]);
                aS[j] = fmaf(h[k], ws[j], aS[j]);
            }
        }
        uint4 p0, p1;
        p0.x = f2bf_rne(aF[0]) | (f2bf_rne(aS[0]) << 16);
        p0.y = f2bf_rne(aF[1]) | (f2bf_rne(aS[1]) << 16);
        p0.z = f2bf_rne(aF[2]) | (f2bf_rne(aS[2]) << 16);
        p0.w = f2bf_rne(aF[3]) | (f2bf_rne(aS[3]) << 16);
        p1.x = f2bf_rne(aF[4]) | (f2bf_rne(aS[4]) << 16);
        p1.y = f2bf_rne(aF[5]) | (f2bf_rne(aS[5]) << 16);
        p1.z = f2bf_rne(aF[6]) | (f2bf_rne(aS[6]) << 16);
        p1.w = f2bf_rne(aF[7]) | (f2bf_rne(aS[7]) << 16);
        uint4* __restrict__ pp = (uint4*)(Pout + (size_t)n * 64 + jt * 8);
        pp[0] = p0;
        pp[1] = p1;
    }
}

// ---------------------------------------------------------------------------
// In-degree histogram (int)
// ---------------------------------------------------------------------------
__global__ __launch_bounds__(256) void deg_kernel(
    const int* __restrict__ dst, int* __restrict__ deg, int E)
{
    int e = blockIdx.x * blockDim.x + threadIdx.x;
    if (e < E) atomicAdd(&deg[dst[e]], 1);
}

// ---------------------------------------------------------------------------
// Three-phase exclusive scan over deg -> rowptr, cursor
// ---------------------------------------------------------------------------
__global__ __launch_bounds__(1024) void scanA_kernel(
    const int* __restrict__ deg, int* __restrict__ iscan,
    int* __restrict__ bsum, int N)
{
    __shared__ int lds[1024];
    int tid = threadIdx.x;
    int gid = blockIdx.x * 1024 + tid;
    int v = (gid < N) ? deg[gid] : 0;
    lds[tid] = v; __syncthreads();
    for (int off = 1; off < 1024; off <<= 1) {
        int t = (tid >= off) ? lds[tid - off] : 0;
        __syncthreads();
        lds[tid] += t;
        __syncthreads();
    }
    if (gid < N) iscan[gid] = lds[tid];
    if (tid == 1023) bsum[blockIdx.x] = lds[1023];
}

__global__ __launch_bounds__(128) void scanB_kernel(
    const int* __restrict__ bsum, int* __restrict__ boff, int nb)
{
    __shared__ int lds[128];
    int t = threadIdx.x;
    int v = (t < nb) ? bsum[t] : 0;
    lds[t] = v; __syncthreads();
    for (int off = 1; off < 128; off <<= 1) {
        int u = (t >= off) ? lds[t - off] : 0;
        __syncthreads();
        lds[t] += u;
        __syncthreads();
    }
    if (t < nb) boff[t] = lds[t] - v;  // exclusive
}

__global__ __launch_bounds__(256) void scanC_kernel(
    const int* __restrict__ iscan, const int* __restrict__ boff,
    const int* __restrict__ deg,
    int* __restrict__ rowptr, int* __restrict__ cursor, int N)
{
    int i = blockIdx.x * blockDim.x + threadIdx.x;
    if (i >= N) return;
    int incl = iscan[i] + boff[i >> 10];
    rowptr[i + 1] = incl;
    cursor[i] = incl - deg[i];
    if (i == 0) rowptr[0] = 0;
}

// ---------------------------------------------------------------------------
// Edge scatter into CSR order, packed (src, ea) int2
// ---------------------------------------------------------------------------
__global__ __launch_bounds__(256) void escatter_kernel(
    const int* __restrict__ src, const int* __restrict__ dst,
    const float* __restrict__ ea, int* __restrict__ cursor,
    int2* __restrict__ e_se, int E)
{
    int e = blockIdx.x * blockDim.x + threadIdx.x;
    if (e >= E) return;
    int pos = atomicAdd(&cursor[dst[e]], 1);
    e_se[pos] = make_int2(src[e], __float_as_int(ea[e]));
}

// ---------------------------------------------------------------------------
// CGConv edge pass, linearized, optional next-layer P fusion (measured:
// +23us/dispatch vs +65us for a standalone pj pass). One wave per node,
// lane = dim; P-epilogue broadcasts hnew via per-wave LDS segment.
// ---------------------------------------------------------------------------
template<bool WITH_P>
__global__ __launch_bounds__(256) void edge_kernel(
    const float* __restrict__ h, const int* __restrict__ rowptr,
    const int2* __restrict__ e_se,
    const unsigned int* __restrict__ P,
    const float* __restrict__ Wf, const float* __restrict__ bfv,
    const float* __restrict__ Ws, const float* __restrict__ bsv,
    const float* __restrict__ WfN, const float* __restrict__ WsN,
    float* __restrict__ hout, unsigned int* __restrict__ Pout)
{
    __shared__ float lds[256];
    int n = blockIdx.x * 4 + (threadIdx.x >> 6);   // grid exactly covers GN
    int d = threadIdx.x & 63;

    // inline dst-projection (wave-uniform float4 broadcast loads)
    const float4* __restrict__ row4 = (const float4*)(h + (size_t)n * 64);
    float qf = bfv[d], qs = bsv[d];
#pragma unroll
    for (int c = 0; c < 16; ++c) {
        float4 v = row4[c];
#pragma unroll
        for (int i = 0; i < 4; ++i) {
            float hk = (i == 0) ? v.x : (i == 1) ? v.y : (i == 2) ? v.z : v.w;
            qf = fmaf(hk, Wf[(c * 4 + i) * 64 + d], qf);
            qs = fmaf(hk, Ws[(c * 4 + i) * 64 + d], qs);
        }
    }
    float wf = Wf[128 * 64 + d];
    float ws = Ws[128 * 64 + d];

    int rb = rowptr[n], re = rowptr[n + 1];
    float agg = 0.f;
#pragma unroll 8
    for (int p = rb; p < re; ++p) {
        int2 se = e_se[p];         // wave-uniform 8B load
        int s = se.x;
        float ea = __int_as_float(se.y);
        unsigned int pv = P[(size_t)s * 64 + d];   // gathered dword
        float pf = __uint_as_float(pv << 16);
        float psv = __uint_as_float(pv & 0xffff0000u);
        float xF = fmaf(ea, wf, qf + pf);
        float xS = fmaf(ea, ws, qs + psv);
        float sig = __builtin_amdgcn_rcpf(1.f + __expf(-xF));
        float t = __expf(-fabsf(xS));
        float sp = fmaxf(xS, 0.f) + __logf(1.f + t);
        agg = fmaf(sig, sp, agg);
    }

    float inv = 1.f / (float)max(re - rb, 1);
    size_t idx = (size_t)n * 64 + d;
    float hnew = fmaxf(h[idx] + agg * inv, 0.f);
    hout[idx] = hnew;

    if (WITH_P) {
        lds[threadIdx.x] = hnew;
        const float4* __restrict__ lds4 =
            (const float4*)&lds[threadIdx.x & 192];
        float pf = 0.f, ps = 0.f, pf1 = 0.f, ps1 = 0.f;
#pragma unroll
        for (int c = 0; c < 16; ++c) {
            float4 v = lds4[c];
            pf  = fmaf(v.x, WfN[(c * 4 + 0) * 64 + d], pf);
            ps  = fmaf(v.x, WsN[(c * 4 + 0) * 64 + d], ps);
            pf1 = fmaf(v.y, WfN[(c * 4 + 1) * 64 + d], pf1);
            ps1 = fmaf(v.y, WsN[(c * 4 + 1) * 64 + d], ps1);
            pf  = fmaf(v.z, WfN[(c * 4 + 2) * 64 + d], pf);
            ps  = fmaf(v.z, WsN[(c * 4 + 2) * 64 + d], ps);
            pf1 = fmaf(v.w, WfN[(c * 4 + 3) * 64 + d], pf1);
            ps1 = fmaf(v.w, WsN[(c * 4 + 3) * 64 + d], ps1);
        }
        Pout[idx] = f2bf_rne(pf + pf1) | (f2bf_rne(ps + ps1) << 16);
    }
}

// ---------------------------------------------------------------------------
// Graph segment starts: bm sorted; gstart[b] = first node of graph b.
// ---------------------------------------------------------------------------
__global__ __launch_bounds__(256) void gstart_kernel(
    const int* __restrict__ bm, int* __restrict__ gstart, int N)
{
    int i = blockIdx.x * blockDim.x + threadIdx.x;
    if (i >= N) return;
    int b = bm[i];
    int prev = (i == 0) ? -1 : bm[i - 1];
    for (int g = prev + 1; g <= b; ++g) gstart[g] = i;
    if (i == N - 1)
        for (int g = b + 1; g <= GB; ++g) gstart[g] = N;
}

// ---------------------------------------------------------------------------
// Segmented mean pool: one block per graph, no atomics.
// ---------------------------------------------------------------------------
__global__ __launch_bounds__(256) void pool_seg_kernel(
    const float* __restrict__ h, const int* __restrict__ gstart,
    float* __restrict__ g)
{
    int b = blockIdx.x;
    int s = gstart[b], e = gstart[b + 1];
    int d = threadIdx.x & 63;
    int w = threadIdx.x >> 6;
    float acc = 0.f;
    for (int n = s + w; n < e; n += 4)
        acc += h[(size_t)n * 64 + d];
    __shared__ float lds[256];
    lds[threadIdx.x] = acc;
    __syncthreads();
    if (w == 0) {
        acc = lds[d] + lds[64 + d] + lds[128 + d] + lds[192 + d];
        g[b * 64 + d] = acc / fmaxf((float)(e - s), 1.f);
    }
}

// ---------------------------------------------------------------------------
// Fused post-MLP (3 relu layers) + final dot + bias. One wave per graph.
// Tiny (128 graphs) -- shuffle chains fine here.
// ---------------------------------------------------------------------------
__global__ __launch_bounds__(256) void postmlp_kernel(
    const float* __restrict__ g,
    const float* __restrict__ W0, const float* __restrict__ b0,
    const float* __restrict__ W1, const float* __restrict__ b1,
    const float* __restrict__ W2, const float* __restrict__ b2,
    const float* __restrict__ Wfin, const float* __restrict__ bfin,
    float* __restrict__ out)
{
    int b = blockIdx.x * 4 + (threadIdx.x >> 6);   // 32 blocks x 4 waves = 128
    int d = threadIdx.x & 63;
    float h = g[(size_t)b * 64 + d];

    float acc = b0[d];
#pragma unroll
    for (int k = 0; k < 64; ++k)
        acc = fmaf(__shfl(h, k, 64), W0[k * 64 + d], acc);
    h = fmaxf(acc, 0.f);

    acc = b1[d];
#pragma unroll
    for (int k = 0; k < 64; ++k)
        acc = fmaf(__shfl(h, k, 64), W1[k * 64 + d], acc);
    h = fmaxf(acc, 0.f);

    acc = b2[d];
#pragma unroll
    for (int k = 0; k < 64; ++k)
        acc = fmaf(__shfl(h, k, 64), W2[k * 64 + d], acc);
    h = fmaxf(acc, 0.f);

    float v = h * Wfin[d];
#pragma unroll
    for (int off = 32; off >= 1; off >>= 1)
        v += __shfl_xor(v, off, 64);
    if (d == 0) out[b] = v + bfin[0];
}

extern "C" void kernel_launch(void* const* d_in, const int* in_sizes, int n_in,
                              void* d_out, int out_size, void* d_ws, size_t ws_size,
                              hipStream_t stream)
{
    const float* X      = (const float*)d_in[0];
    const int*   eidx   = (const int*)d_in[1];
    const float* ea     = (const float*)d_in[3];
    const int*   bm     = (const int*)d_in[4];
    const float* pre_W0 = (const float*)d_in[5];
    const float* pre_b0 = (const float*)d_in[6];
    const float* pre_W1 = (const float*)d_in[7];
    const float* pre_b1 = (const float*)d_in[8];
    const float* pre_W2 = (const float*)d_in[9];
    const float* pre_b2 = (const float*)d_in[10];
    const float* cg_Wf  = (const float*)d_in[11];
    const float* cg_bf  = (const float*)d_in[12];
    const float* cg_Ws  = (const float*)d_in[13];
    const float* cg_bs  = (const float*)d_in[14];
    const float* post_W0 = (const float*)d_in[15];
    const float* post_b0 = (const float*)d_in[16];
    const float* post_W1 = (const float*)d_in[17];
    const float* post_b1 = (const float*)d_in[18];
    const float* post_W2 = (const float*)d_in[19];
    const float* post_b2 = (const float*)d_in[20];
    const float* post_Wf = (const float*)d_in[21];
    const float* post_bf = (const float*)d_in[22];

    const int* src = eidx;
    const int* dst = eidx + GE;

    // ---- workspace carve-up ----
    const size_t N64 = (size_t)GN * 64;
    float* hA    = (float*)d_ws;            // N*64
    float* hB    = hA + N64;                // N*64
    unsigned int* P = (unsigned int*)(hB + N64);  // N*64 packed bf16x2
    int* deg_i   = (int*)(P + N64);         // N
    int* iscan   = deg_i + GN;              // N
    int* bsum    = iscan + GN;              // 128
    int* boff    = bsum + 128;              // 128
    int* rowptr  = boff + 128;              // N+2 (padded so e_se is 8B-aligned)
    int* cursor  = rowptr + GN + 2;         // N
    int2* e_se   = (int2*)(cursor + GN);    // E int2 (8B-aligned)
    int* gstart  = (int*)(e_se + GE);       // B+1
    float* g0    = (float*)(gstart + GB + 1); // B*64

    const int TPB = 256;
    int gridE  = (GE + TPB - 1) / TPB;
    int gridN  = (GN + TPB - 1) / TPB;         // 391 (lane=node grid)
    int gridND = ((GN * 64) + TPB - 1) / TPB;  // 25000 (edge grid)
    int scanBlocks = (GN + 1023) / 1024;       // 98

    // per-layer weight pointers
    const float* Wf0 = cg_Wf;
    const float* Ws0 = cg_Ws;
    const float* Wf1 = cg_Wf + (size_t)1 * GZ * GD;
    const float* Ws1 = cg_Ws + (size_t)1 * GZ * GD;
    const float* Wf2 = cg_Wf + (size_t)2 * GZ * GD;
    const float* Ws2 = cg_Ws + (size_t)2 * GZ * GD;

    // fused pre-MLP (registers chain the 3 layers) + P0
    premlp_kernel<<<gridN, TPB, 0, stream>>>(
        X, pre_W0, pre_b0, pre_W1, pre_b1, pre_W2, pre_b2,
        Wf0 + 64 * 64, Ws0 + 64 * 64, hA, P, GN);

    // degree + CSR build
    hipMemsetAsync(deg_i, 0, GN * sizeof(int), stream);
    deg_kernel<<<gridE, TPB, 0, stream>>>(dst, deg_i, GE);
    scanA_kernel<<<scanBlocks, 1024, 0, stream>>>(deg_i, iscan, bsum, GN);
    scanB_kernel<<<1, 128, 0, stream>>>(bsum, boff, scanBlocks);
    scanC_kernel<<<gridN, TPB, 0, stream>>>(iscan, boff, deg_i, rowptr, cursor, GN);
    escatter_kernel<<<gridE, TPB, 0, stream>>>(src, dst, ea, cursor, e_se, GE);

    // graph segment starts (bm sorted)
    gstart_kernel<<<gridN, TPB, 0, stream>>>(bm, gstart, GN);

    // CGConv layers: edge0 (emits P1), edge1 (emits P2), edge2 (plain)
    edge_kernel<true><<<gridND, TPB, 0, stream>>>(
        hA, rowptr, e_se, P,
        Wf0, cg_bf, Ws0, cg_bs,
        Wf1 + 64 * 64, Ws1 + 64 * 64, hB, P);
    edge_kernel<true><<<gridND, TPB, 0, stream>>>(
        hB, rowptr, e_se, P,
        Wf1, cg_bf + GD, Ws1, cg_bs + GD,
        Wf2 + 64 * 64, Ws2 + 64 * 64, hA, P);
    edge_kernel<false><<<gridND, TPB, 0, stream>>>(
        hA, rowptr, e_se, P,
        Wf2, cg_bf + 2 * GD, Ws2, cg_bs + 2 * GD,
        nullptr, nullptr, hB, nullptr);

    // segmented mean pool (no atomics)
    pool_seg_kernel<<<GB, TPB, 0, stream>>>(hB, gstart, g0);

    // fused post-MLP + final projection
    postmlp_kernel<<<GB / 4, TPB, 0, stream>>>(
        g0, post_W0, post_b0, post_W1, post_b1, post_W2, post_b2,
        post_Wf, post_bf, (float*)d_out);
}

// Round 11
// 1193.745 us; speedup vs baseline: 1.1162x; 1.1162x over previous
//
#include <hip/hip_runtime.h>
#include <hip/hip_bf16.h>
#include <math.h>

// Problem constants (fixed by the reference)
#define GN 100000   // nodes
#define GE 1200000  // edges
#define GB 128      // graphs
#define GF 92       // raw features
#define GD 64       // hidden dim
#define GL 3        // CGConv layers
#define GZ 129      // 2*D+1

// round-to-nearest-even fp32 -> bf16 (returned in low 16 bits)
__device__ __forceinline__ unsigned int f2bf_rne(float x)
{
    unsigned int u = __float_as_uint(x);
    u += 0x7fffu + ((u >> 16) & 1u);
    return u >> 16;
}

// ---------------------------------------------------------------------------
// Fused pre-MLP (3 layers) + P0, lane = node. Layers chain through per-lane
// registers; weight addresses lane-invariant -> scalar s_load streams.
// (Measured R10: replaced ~280us of separate dense kernels with ~120us.)
// ---------------------------------------------------------------------------
__global__ __launch_bounds__(256) void premlp_kernel(
    const float* __restrict__ X,
    const float* __restrict__ W0, const float* __restrict__ b0,
    const float* __restrict__ W1, const float* __restrict__ b1,
    const float* __restrict__ W2, const float* __restrict__ b2,
    const float* __restrict__ WfN, const float* __restrict__ WsN,
    float* __restrict__ hout, unsigned int* __restrict__ Pout, int N)
{
    int n = blockIdx.x * 256 + threadIdx.x;   // lane = node
    if (n >= N) return;

    float h[64], h2[64];

    // layer 0: K=92
    const float4* __restrict__ row4 = (const float4*)(X + (size_t)n * GF);
#pragma unroll
    for (int jt = 0; jt < 8; ++jt) {
        float acc[8];
#pragma unroll
        for (int j = 0; j < 8; ++j) acc[j] = b0[jt * 8 + j];
        for (int c = 0; c < 23; ++c) {
            float4 v = row4[c];
            const float* __restrict__ w = W0 + (c * 4) * 64 + jt * 8;  // uniform
#pragma unroll
            for (int j = 0; j < 8; ++j) {
                acc[j] = fmaf(v.x, w[j], acc[j]);
                acc[j] = fmaf(v.y, w[64 + j], acc[j]);
                acc[j] = fmaf(v.z, w[128 + j], acc[j]);
                acc[j] = fmaf(v.w, w[192 + j], acc[j]);
            }
        }
#pragma unroll
        for (int j = 0; j < 8; ++j) h[jt * 8 + j] = fmaxf(acc[j], 0.f);
    }

    // layer 1
#pragma unroll
    for (int jt = 0; jt < 8; ++jt) {
        float acc[8];
#pragma unroll
        for (int j = 0; j < 8; ++j) acc[j] = b1[jt * 8 + j];
#pragma unroll
        for (int k = 0; k < 64; ++k) {
            const float* __restrict__ w = W1 + k * 64 + jt * 8;
#pragma unroll
            for (int j = 0; j < 8; ++j) acc[j] = fmaf(h[k], w[j], acc[j]);
        }
#pragma unroll
        for (int j = 0; j < 8; ++j) h2[jt * 8 + j] = fmaxf(acc[j], 0.f);
    }

    // layer 2
#pragma unroll
    for (int jt = 0; jt < 8; ++jt) {
        float acc[8];
#pragma unroll
        for (int j = 0; j < 8; ++j) acc[j] = b2[jt * 8 + j];
#pragma unroll
        for (int k = 0; k < 64; ++k) {
            const float* __restrict__ w = W2 + k * 64 + jt * 8;
#pragma unroll
            for (int j = 0; j < 8; ++j) acc[j] = fmaf(h2[k], w[j], acc[j]);
        }
#pragma unroll
        for (int j = 0; j < 8; ++j) h[jt * 8 + j] = fmaxf(acc[j], 0.f);
    }

    // store h
    float4* __restrict__ op = (float4*)(hout + (size_t)n * 64);
#pragma unroll
    for (int c = 0; c < 16; ++c)
        op[c] = make_float4(h[c * 4], h[c * 4 + 1], h[c * 4 + 2], h[c * 4 + 3]);

    // P0 projection (src half of both layer-0 gates), packed bf16
#pragma unroll
    for (int jt = 0; jt < 8; ++jt) {
        float aF[8], aS[8];
#pragma unroll
        for (int j = 0; j < 8; ++j) { aF[j] = 0.f; aS[j] = 0.f; }
#pragma unroll
        for (int k = 0; k < 64; ++k) {
            const float* __restrict__ wf = WfN + k * 64 + jt * 8;
            const float* __restrict__ ws = WsN + k * 64 + jt * 8;
#pragma unroll
            for (int j = 0; j < 8; ++j) {
                aF[j] = fmaf(h[k], wf[j], aF[j]);
                aS[j] = fmaf(h[k], ws[j], aS[j]);
            }
        }
        uint4 p0, p1;
        p0.x = f2bf_rne(aF[0]) | (f2bf_rne(aS[0]) << 16);
        p0.y = f2bf_rne(aF[1]) | (f2bf_rne(aS[1]) << 16);
        p0.z = f2bf_rne(aF[2]) | (f2bf_rne(aS[2]) << 16);
        p0.w = f2bf_rne(aF[3]) | (f2bf_rne(aS[3]) << 16);
        p1.x = f2bf_rne(aF[4]) | (f2bf_rne(aS[4]) << 16);
        p1.y = f2bf_rne(aF[5]) | (f2bf_rne(aS[5]) << 16);
        p1.z = f2bf_rne(aF[6]) | (f2bf_rne(aS[6]) << 16);
        p1.w = f2bf_rne(aF[7]) | (f2bf_rne(aS[7]) << 16);
        uint4* __restrict__ pp = (uint4*)(Pout + (size_t)n * 64 + jt * 8);
        pp[0] = p0;
        pp[1] = p1;
    }
}

// ---------------------------------------------------------------------------
// P projection (src half of both gates), lane = node, packed bf16 output.
// Measured R9: ~65us. Cheaper than fusing into edge epilogue (+140us, R10).
// ---------------------------------------------------------------------------
__global__ __launch_bounds__(256) void pj_kernel(
    const float* __restrict__ h,
    const float* __restrict__ Wf, const float* __restrict__ Ws,
    unsigned int* __restrict__ P, int N)
{
    int n = blockIdx.x * 256 + threadIdx.x;   // lane = node
    if (n >= N) return;
    const float4* __restrict__ row4 = (const float4*)(h + (size_t)n * 64);

    for (int jt = 0; jt < 8; ++jt) {
        float aF[8], aS[8];
#pragma unroll
        for (int j = 0; j < 8; ++j) { aF[j] = 0.f; aS[j] = 0.f; }
        for (int c = 0; c < 16; ++c) {
            float4 v = row4[c];
            const float* __restrict__ wf = Wf + (64 + c * 4) * 64 + jt * 8;
            const float* __restrict__ ws = Ws + (64 + c * 4) * 64 + jt * 8;
#pragma unroll
            for (int j = 0; j < 8; ++j) {
                aF[j] = fmaf(v.x, wf[j], aF[j]);
                aF[j] = fmaf(v.y, wf[64 + j], aF[j]);
                aF[j] = fmaf(v.z, wf[128 + j], aF[j]);
                aF[j] = fmaf(v.w, wf[192 + j], aF[j]);
                aS[j] = fmaf(v.x, ws[j], aS[j]);
                aS[j] = fmaf(v.y, ws[64 + j], aS[j]);
                aS[j] = fmaf(v.z, ws[128 + j], aS[j]);
                aS[j] = fmaf(v.w, ws[192 + j], aS[j]);
            }
        }
        uint4 p0, p1;
        p0.x = f2bf_rne(aF[0]) | (f2bf_rne(aS[0]) << 16);
        p0.y = f2bf_rne(aF[1]) | (f2bf_rne(aS[1]) << 16);
        p0.z = f2bf_rne(aF[2]) | (f2bf_rne(aS[2]) << 16);
        p0.w = f2bf_rne(aF[3]) | (f2bf_rne(aS[3]) << 16);
        p1.x = f2bf_rne(aF[4]) | (f2bf_rne(aS[4]) << 16);
        p1.y = f2bf_rne(aF[5]) | (f2bf_rne(aS[5]) << 16);
        p1.z = f2bf_rne(aF[6]) | (f2bf_rne(aS[6]) << 16);
        p1.w = f2bf_rne(aF[7]) | (f2bf_rne(aS[7]) << 16);
        uint4* __restrict__ pp = (uint4*)(P + (size_t)n * 64 + jt * 8);
        pp[0] = p0;
        pp[1] = p1;
    }
}

// ---------------------------------------------------------------------------
// In-degree histogram (int)
// ---------------------------------------------------------------------------
__global__ __launch_bounds__(256) void deg_kernel(
    const int* __restrict__ dst, int* __restrict__ deg, int E)
{
    int e = blockIdx.x * blockDim.x + threadIdx.x;
    if (e < E) atomicAdd(&deg[dst[e]], 1);
}

// ---------------------------------------------------------------------------
// Three-phase exclusive scan over deg -> rowptr, cursor
// ---------------------------------------------------------------------------
__global__ __launch_bounds__(1024) void scanA_kernel(
    const int* __restrict__ deg, int* __restrict__ iscan,
    int* __restrict__ bsum, int N)
{
    __shared__ int lds[1024];
    int tid = threadIdx.x;
    int gid = blockIdx.x * 1024 + tid;
    int v = (gid < N) ? deg[gid] : 0;
    lds[tid] = v; __syncthreads();
    for (int off = 1; off < 1024; off <<= 1) {
        int t = (tid >= off) ? lds[tid - off] : 0;
        __syncthreads();
        lds[tid] += t;
        __syncthreads();
    }
    if (gid < N) iscan[gid] = lds[tid];
    if (tid == 1023) bsum[blockIdx.x] = lds[1023];
}

__global__ __launch_bounds__(128) void scanB_kernel(
    const int* __restrict__ bsum, int* __restrict__ boff, int nb)
{
    __shared__ int lds[128];
    int t = threadIdx.x;
    int v = (t < nb) ? bsum[t] : 0;
    lds[t] = v; __syncthreads();
    for (int off = 1; off < 128; off <<= 1) {
        int u = (t >= off) ? lds[t - off] : 0;
        __syncthreads();
        lds[t] += u;
        __syncthreads();
    }
    if (t < nb) boff[t] = lds[t] - v;  // exclusive
}

__global__ __launch_bounds__(256) void scanC_kernel(
    const int* __restrict__ iscan, const int* __restrict__ boff,
    const int* __restrict__ deg,
    int* __restrict__ rowptr, int* __restrict__ cursor, int N)
{
    int i = blockIdx.x * blockDim.x + threadIdx.x;
    if (i >= N) return;
    int incl = iscan[i] + boff[i >> 10];
    rowptr[i + 1] = incl;
    cursor[i] = incl - deg[i];
    if (i == 0) rowptr[0] = 0;
}

// ---------------------------------------------------------------------------
// Edge scatter into CSR order, packed (src, ea) int2
// ---------------------------------------------------------------------------
__global__ __launch_bounds__(256) void escatter_kernel(
    const int* __restrict__ src, const int* __restrict__ dst,
    const float* __restrict__ ea, int* __restrict__ cursor,
    int2* __restrict__ e_se, int E)
{
    int e = blockIdx.x * blockDim.x + threadIdx.x;
    if (e >= E) return;
    int pos = atomicAdd(&cursor[dst[e]], 1);
    e_se[pos] = make_int2(src[e], __float_as_int(ea[e]));
}

// ---------------------------------------------------------------------------
// CGConv edge pass (measured-best plain form: VGPR 36, occ 66%, 201us).
// One wave per node, lane = dim.
// ---------------------------------------------------------------------------
__global__ __launch_bounds__(256) void edge_kernel(
    const float* __restrict__ h, const int* __restrict__ rowptr,
    const int2* __restrict__ e_se,
    const unsigned int* __restrict__ P,
    const float* __restrict__ Wf, const float* __restrict__ bfv,
    const float* __restrict__ Ws, const float* __restrict__ bsv,
    float* __restrict__ hout)
{
    int n = blockIdx.x * 4 + (threadIdx.x >> 6);   // grid exactly covers GN
    int d = threadIdx.x & 63;

    // inline dst-projection (wave-uniform float4 broadcast loads)
    const float4* __restrict__ row4 = (const float4*)(h + (size_t)n * 64);
    float qf = bfv[d], qs = bsv[d];
#pragma unroll
    for (int c = 0; c < 16; ++c) {
        float4 v = row4[c];
#pragma unroll
        for (int i = 0; i < 4; ++i) {
            float hk = (i == 0) ? v.x : (i == 1) ? v.y : (i == 2) ? v.z : v.w;
            qf = fmaf(hk, Wf[(c * 4 + i) * 64 + d], qf);
            qs = fmaf(hk, Ws[(c * 4 + i) * 64 + d], qs);
        }
    }
    float wf = Wf[128 * 64 + d];
    float ws = Ws[128 * 64 + d];

    int rb = rowptr[n], re = rowptr[n + 1];
    float agg = 0.f;
#pragma unroll 8
    for (int p = rb; p < re; ++p) {
        int2 se = e_se[p];         // wave-uniform 8B load
        int s = se.x;
        float ea = __int_as_float(se.y);
        unsigned int pv = P[(size_t)s * 64 + d];   // gathered dword
        float pf = __uint_as_float(pv << 16);
        float psv = __uint_as_float(pv & 0xffff0000u);
        float xF = fmaf(ea, wf, qf + pf);
        float xS = fmaf(ea, ws, qs + psv);
        float sig = __builtin_amdgcn_rcpf(1.f + __expf(-xF));
        float t = __expf(-fabsf(xS));
        float sp = fmaxf(xS, 0.f) + __logf(1.f + t);
        agg = fmaf(sig, sp, agg);
    }

    float inv = 1.f / (float)max(re - rb, 1);
    size_t idx = (size_t)n * 64 + d;
    hout[idx] = fmaxf(h[idx] + agg * inv, 0.f);
}

// ---------------------------------------------------------------------------
// Graph segment starts: bm sorted; gstart[b] = first node of graph b.
// ---------------------------------------------------------------------------
__global__ __launch_bounds__(256) void gstart_kernel(
    const int* __restrict__ bm, int* __restrict__ gstart, int N)
{
    int i = blockIdx.x * blockDim.x + threadIdx.x;
    if (i >= N) return;
    int b = bm[i];
    int prev = (i == 0) ? -1 : bm[i - 1];
    for (int g = prev + 1; g <= b; ++g) gstart[g] = i;
    if (i == N - 1)
        for (int g = b + 1; g <= GB; ++g) gstart[g] = N;
}

// ---------------------------------------------------------------------------
// Segmented mean pool: one block per graph, no atomics.
// ---------------------------------------------------------------------------
__global__ __launch_bounds__(256) void pool_seg_kernel(
    const float* __restrict__ h, const int* __restrict__ gstart,
    float* __restrict__ g)
{
    int b = blockIdx.x;
    int s = gstart[b], e = gstart[b + 1];
    int d = threadIdx.x & 63;
    int w = threadIdx.x >> 6;
    float acc = 0.f;
    for (int n = s + w; n < e; n += 4)
        acc += h[(size_t)n * 64 + d];
    __shared__ float lds[256];
    lds[threadIdx.x] = acc;
    __syncthreads();
    if (w == 0) {
        acc = lds[d] + lds[64 + d] + lds[128 + d] + lds[192 + d];
        g[b * 64 + d] = acc / fmaxf((float)(e - s), 1.f);
    }
}

// ---------------------------------------------------------------------------
// Fused post-MLP (3 relu layers) + final dot + bias. One wave per graph.
// ---------------------------------------------------------------------------
__global__ __launch_bounds__(256) void postmlp_kernel(
    const float* __restrict__ g,
    const float* __restrict__ W0, const float* __restrict__ b0,
    const float* __restrict__ W1, const float* __restrict__ b1,
    const float* __restrict__ W2, const float* __restrict__ b2,
    const float* __restrict__ Wfin, const float* __restrict__ bfin,
    float* __restrict__ out)
{
    int b = blockIdx.x * 4 + (threadIdx.x >> 6);   // 32 blocks x 4 waves = 128
    int d = threadIdx.x & 63;
    float h = g[(size_t)b * 64 + d];

    float acc = b0[d];
#pragma unroll
    for (int k = 0; k < 64; ++k)
        acc = fmaf(__shfl(h, k, 64), W0[k * 64 + d], acc);
    h = fmaxf(acc, 0.f);

    acc = b1[d];
#pragma unroll
    for (int k = 0; k < 64; ++k)
        acc = fmaf(__shfl(h, k, 64), W1[k * 64 + d], acc);
    h = fmaxf(acc, 0.f);

    acc = b2[d];
#pragma unroll
    for (int k = 0; k < 64; ++k)
        acc = fmaf(__shfl(h, k, 64), W2[k * 64 + d], acc);
    h = fmaxf(acc, 0.f);

    float v = h * Wfin[d];
#pragma unroll
    for (int off = 32; off >= 1; off >>= 1)
        v += __shfl_xor(v, off, 64);
    if (d == 0) out[b] = v + bfin[0];
}

extern "C" void kernel_launch(void* const* d_in, const int* in_sizes, int n_in,
                              void* d_out, int out_size, void* d_ws, size_t ws_size,
                              hipStream_t stream)
{
    const float* X      = (const float*)d_in[0];
    const int*   eidx   = (const int*)d_in[1];
    const float* ea     = (const float*)d_in[3];
    const int*   bm     = (const int*)d_in[4];
    const float* pre_W0 = (const float*)d_in[5];
    const float* pre_b0 = (const float*)d_in[6];
    const float* pre_W1 = (const float*)d_in[7];
    const float* pre_b1 = (const float*)d_in[8];
    const float* pre_W2 = (const float*)d_in[9];
    const float* pre_b2 = (const float*)d_in[10];
    const float* cg_Wf  = (const float*)d_in[11];
    const float* cg_bf  = (const float*)d_in[12];
    const float* cg_Ws  = (const float*)d_in[13];
    const float* cg_bs  = (const float*)d_in[14];
    const float* post_W0 = (const float*)d_in[15];
    const float* post_b0 = (const float*)d_in[16];
    const float* post_W1 = (const float*)d_in[17];
    const float* post_b1 = (const float*)d_in[18];
    const float* post_W2 = (const float*)d_in[19];
    const float* post_b2 = (const float*)d_in[20];
    const float* post_Wf = (const float*)d_in[21];
    const float* post_bf = (const float*)d_in[22];

    const int* src = eidx;
    const int* dst = eidx + GE;

    // ---- workspace carve-up ----
    const size_t N64 = (size_t)GN * 64;
    float* hA    = (float*)d_ws;            // N*64
    float* hB    = hA + N64;                // N*64
    unsigned int* P = (unsigned int*)(hB + N64);  // N*64 packed bf16x2
    int* deg_i   = (int*)(P + N64);         // N
    int* iscan   = deg_i + GN;              // N
    int* bsum    = iscan + GN;              // 128
    int* boff    = bsum + 128;              // 128
    int* rowptr  = boff + 128;              // N+2 (padded so e_se is 8B-aligned)
    int* cursor  = rowptr + GN + 2;         // N
    int2* e_se   = (int2*)(cursor + GN);    // E int2 (8B-aligned)
    int* gstart  = (int*)(e_se + GE);       // B+1
    float* g0    = (float*)(gstart + GB + 1); // B*64

    const int TPB = 256;
    int gridE  = (GE + TPB - 1) / TPB;
    int gridN  = (GN + TPB - 1) / TPB;         // 391 (lane=node grid)
    int gridND = ((GN * 64) + TPB - 1) / TPB;  // 25000 (edge grid)
    int scanBlocks = (GN + 1023) / 1024;       // 98

    // per-layer weight pointers
    const float* Wf0 = cg_Wf;
    const float* Ws0 = cg_Ws;
    const float* Wf1 = cg_Wf + (size_t)1 * GZ * GD;
    const float* Ws1 = cg_Ws + (size_t)1 * GZ * GD;
    const float* Wf2 = cg_Wf + (size_t)2 * GZ * GD;
    const float* Ws2 = cg_Ws + (size_t)2 * GZ * GD;

    // fused pre-MLP (registers chain the 3 layers) + P0
    premlp_kernel<<<gridN, TPB, 0, stream>>>(
        X, pre_W0, pre_b0, pre_W1, pre_b1, pre_W2, pre_b2,
        Wf0 + 64 * 64, Ws0 + 64 * 64, hA, P, GN);

    // degree + CSR build
    hipMemsetAsync(deg_i, 0, GN * sizeof(int), stream);
    deg_kernel<<<gridE, TPB, 0, stream>>>(dst, deg_i, GE);
    scanA_kernel<<<scanBlocks, 1024, 0, stream>>>(deg_i, iscan, bsum, GN);
    scanB_kernel<<<1, 128, 0, stream>>>(bsum, boff, scanBlocks);
    scanC_kernel<<<gridN, TPB, 0, stream>>>(iscan, boff, deg_i, rowptr, cursor, GN);
    escatter_kernel<<<gridE, TPB, 0, stream>>>(src, dst, ea, cursor, e_se, GE);

    // graph segment starts (bm sorted)
    gstart_kernel<<<gridN, TPB, 0, stream>>>(bm, gstart, GN);

    // CGConv layers: plain edge + standalone pj for next layer
    edge_kernel<<<gridND, TPB, 0, stream>>>(
        hA, rowptr, e_se, P, Wf0, cg_bf, Ws0, cg_bs, hB);
    pj_kernel<<<gridN, TPB, 0, stream>>>(hB, Wf1, Ws1, P, GN);
    edge_kernel<<<gridND, TPB, 0, stream>>>(
        hB, rowptr, e_se, P, Wf1, cg_bf + GD, Ws1, cg_bs + GD, hA);
    pj_kernel<<<gridN, TPB, 0, stream>>>(hA, Wf2, Ws2, P, GN);
    edge_kernel<<<gridND, TPB, 0, stream>>>(
        hA, rowptr, e_se, P, Wf2, cg_bf + 2 * GD, Ws2, cg_bs + 2 * GD, hB);

    // segmented mean pool (no atomics)
    pool_seg_kernel<<<GB, TPB, 0, stream>>>(hB, gstart, g0);

    // fused post-MLP + final projection
    postmlp_kernel<<<GB / 4, TPB, 0, stream>>>(
        g0, post_W0, post_b0, post_W1, post_b1, post_W2, post_b2,
        post_Wf, post_bf, (float*)d_out);
}